// Round 7
// baseline (129.382 us; speedup 1.0000x reference)
//
#include <hip/hip_runtime.h>
#include <hip/hip_bf16.h>
#include <stdint.h>

// Problem constants
#define BDIM 4096
#define CDIM 10000
#define DDIM 512
#define CPAD 10112  // 79 * 128, padded N so GEMM loads need no guards
#define NT 16       // K tiles (512 / 32)

typedef __bf16 bf16_t;
typedef __attribute__((ext_vector_type(2))) __bf16 bf16x2;
typedef __attribute__((ext_vector_type(8))) __bf16 bf16x8;
typedef __attribute__((ext_vector_type(2))) float f32x2;
typedef __attribute__((ext_vector_type(4))) float f32x4;

__device__ __forceinline__ void gl_lds16(const void* g, void* s) {
  // async global->LDS, 16B per lane; LDS dest = wave-uniform base + lane*16
  __builtin_amdgcn_global_load_lds(
      (const __attribute__((address_space(1))) void*)g,
      (__attribute__((address_space(3))) void*)s, 16, 0, 0);
}

// --- fused prep: rows [0,BDIM) = feat, rows [BDIM,BDIM+CPAD) = weights ---
__global__ __launch_bounds__(256) void prep(
    const float* __restrict__ feat, const float* __restrict__ w,
    bf16_t* __restrict__ fb, bf16_t* __restrict__ wb,
    float* __restrict__ f2, float* __restrict__ w2,
    float* __restrict__ wout) {
  const int b = blockIdx.x;
  const int t = threadIdx.x;
  __shared__ float red[4];
  if (b < BDIM) {
    const f32x2 v = ((const f32x2*)(feat + (size_t)b * DDIM))[t];
    bf16x2 o;
    o.x = (__bf16)v.x;
    o.y = (__bf16)v.y;
    ((bf16x2*)fb)[(size_t)b * (DDIM / 2) + t] = o;
    float ss = v.x * v.x + v.y * v.y;
#pragma unroll
    for (int off = 32; off > 0; off >>= 1) ss += __shfl_down(ss, off);
    if ((t & 63) == 0) red[t >> 6] = ss;
    __syncthreads();
    if (t == 0) f2[b] = red[0] + red[1] + red[2] + red[3];
  } else {
    const int row = b - BDIM;
    if (row < CDIM) {
      const f32x2 v = ((const f32x2*)(w + (size_t)row * DDIM))[t];
      __builtin_nontemporal_store(v, (f32x2*)(wout + (size_t)row * DDIM) + t);
      bf16x2 o;
      o.x = (__bf16)v.x;
      o.y = (__bf16)v.y;
      ((bf16x2*)wb)[(size_t)row * (DDIM / 2) + t] = o;
      float ss = v.x * v.x + v.y * v.y;
#pragma unroll
      for (int off = 32; off > 0; off >>= 1) ss += __shfl_down(ss, off);
      if ((t & 63) == 0) red[t >> 6] = ss;
      __syncthreads();
      if (t == 0) w2[row] = red[0] + red[1] + red[2] + red[3];
    } else {
      bf16x2 z;
      z.x = (__bf16)0.0f;
      z.y = (__bf16)0.0f;
      ((bf16x2*)wb)[(size_t)row * (DDIM / 2) + t] = z;
      if (t == 0) w2[row] = 0.0f;
    }
  }
}

// --- main GEMM + RBF epilogue ---
// 128x128 tile, BK=32, 4 waves (2x2), mfma(wfrag, ffrag) operand-swapped.
// 3-buffer LDS round-robin, counted vmcnt(4), setprio, LDS-staged coalesced
// epilogue, bm-fastest XCD ordering (R5 config — best so far).
// R7 single variable: epilogue stores are CACHED (plain), not nontemporal.
// NT bypasses L2 (16 B/lane granules straight to HBM); cached stores let L2
// aggregate full 128 B dirty lines and stream evictions at fill-rate
// (harness fills hit 6.9 TB/s through this path on the same buffer).
__global__ __launch_bounds__(256, 3) void rbf_gemm(
    const bf16_t* __restrict__ A,   // [4096][512] bf16  (feat)
    const bf16_t* __restrict__ Bw,  // [10112][512] bf16 (weights, padded)
    const float* __restrict__ f2g, const float* __restrict__ w2g,
    float* __restrict__ out) {
  __shared__ __align__(16) char pool[49152];  // At(24576) | Bt(24576)
  bf16_t* At = (bf16_t*)pool;
  bf16_t* Bt = (bf16_t*)(pool + 24576);
  __shared__ float f2s[128];
  __shared__ float w2s[128];

  // 1-D grid, bijective XCD swizzle (nwg = 2528 = 8*316), bm fastest
  // (R5/R6 A/B: bm-fastest wins — concurrent blocks share the B-tile).
  const int bid = blockIdx.x;
  const int wg = (bid & 7) * (2528 / 8) + (bid >> 3);
  const int bm = wg & 31;  // 0..31 (M tiles) -- fastest within XCD chunk
  const int bn = wg >> 5;  // 0..78 (N tiles)
  const int t = threadIdx.x;
  const int lane = t & 63;

  if (t < 128)
    f2s[t] = f2g[bm * 128 + t];
  else
    w2s[t - 128] = w2g[bn * 128 + (t - 128)];

  // staging addressing: 4 threads x 16B per 32-elem row; 64 rows per call
  const int sr = t >> 2;
  const int sc = (t & 3) * 8;
  const bf16_t* ga0 = A + (size_t)(bm * 128 + sr) * DDIM + sc;
  const bf16_t* ga1 = ga0 + (size_t)64 * DDIM;
  const bf16_t* gb0 = Bw + (size_t)(bn * 128 + sr) * DDIM + sc;
  const bf16_t* gb1 = gb0 + (size_t)64 * DDIM;

  const int wv = t >> 6;
  const int wm = (wv >> 1) * 64;  // feat group of this wave
  const int wn = (wv & 1) * 64;   // weight group of this wave
  const int fr = lane & 15;
  const int k8 = (lane >> 4) * 8;

#define STAGE(boff, kt)                              \
  do {                                               \
    const int k0_ = (kt) * 32;                       \
    gl_lds16(ga0 + k0_, At + (boff) + t * 8);        \
    gl_lds16(ga1 + k0_, At + (boff) + 2048 + t * 8); \
    gl_lds16(gb0 + k0_, Bt + (boff) + t * 8);        \
    gl_lds16(gb1 + k0_, Bt + (boff) + 2048 + t * 8); \
  } while (0)

  f32x4 acc[4][4];
#pragma unroll
  for (int i = 0; i < 4; ++i)
#pragma unroll
    for (int j = 0; j < 4; ++j) acc[i][j] = (f32x4){0.f, 0.f, 0.f, 0.f};

  // prologue: tiles 0 and 1 in flight; full sync drains them + f2s/w2s
  STAGE(0, 0);
  STAGE(4096, 1);
  __syncthreads();

  int o0 = 0, o1 = 4096, o2 = 8192;
#pragma unroll
  for (int kt = 0; kt < NT; ++kt) {
    if (kt + 2 < NT) STAGE(o2, kt + 2);  // issue prefetch FIRST
    bf16x8 af[4], wf[4];
#pragma unroll
    for (int mi = 0; mi < 4; ++mi)
      af[mi] = *(const bf16x8*)(At + o0 + (wm + mi * 16 + fr) * 32 + k8);
#pragma unroll
    for (int ni = 0; ni < 4; ++ni)
      wf[ni] = *(const bf16x8*)(Bt + o0 + (wn + ni * 16 + fr) * 32 + k8);
    __builtin_amdgcn_s_setprio(1);
#pragma unroll
    for (int mi = 0; mi < 4; ++mi)
#pragma unroll
      for (int ni = 0; ni < 4; ++ni)
        acc[mi][ni] = __builtin_amdgcn_mfma_f32_16x16x32_bf16(
            wf[ni], af[mi], acc[mi][ni], 0, 0, 0);  // swapped: D = W x F^T
    __builtin_amdgcn_s_setprio(0);
    if (kt < NT - 1) {
      // tile kt+1 must have landed; tile kt+2 (4 loads) stays in flight
      if (kt + 2 < NT)
        asm volatile("s_waitcnt vmcnt(4)" ::: "memory");
      else
        asm volatile("s_waitcnt vmcnt(0)" ::: "memory");
      __builtin_amdgcn_s_barrier();
    }
    const int tmp = o0;
    o0 = o1;
    o1 = o2;
    o2 = tmp;
  }

  __syncthreads();  // staging LDS now dead -> reuse as reshuffle tile

  // Coalesced epilogue. resh = 64 rows x 132 floats (pad: 2-way bank alias
  // only). Pass p covers output rows [p*64, p*64+64), produced by the two
  // waves with wm == p*64.
  float* resh = (float*)pool;  // 64*132*4 = 33792 B < 49152 B
  const size_t BC = (size_t)BDIM * CDIM;
  const int m_l = lane & 15;
  const int c_l = (lane >> 4) * 4;

  for (int p = 0; p < 2; ++p) {
    if ((wv >> 1) == p) {
#pragma unroll
      for (int mi = 0; mi < 4; ++mi) {
        const int rl = mi * 16 + m_l;  // row within this 64-row half
        const float frow = f2s[wm + rl];
#pragma unroll
        for (int ni = 0; ni < 4; ++ni) {
          const int cl = wn + ni * 16 + c_l;
          f32x4 st;
#pragma unroll
          for (int j = 0; j < 4; ++j) {
            float m = frow + w2s[cl + j] - 2.0f * acc[mi][ni][j];
            m = fmaxf(m, 0.0f);
            st[j] = __expf(-0.01f * m);
          }
          *(f32x4*)(resh + rl * 132 + cl) = st;
        }
      }
    }
    __syncthreads();
    // stream 64 rows x 128 cols: 32 lanes x float4 = 512 B contiguous/row
    {
      const int rr = t >> 5;         // 0..7
      const int cc = (t & 31) * 4;   // 0..124
      const int gcol = bn * 128 + cc;
      if (gcol < CDIM) {
#pragma unroll
        for (int it = 0; it < 8; ++it) {
          const int r = it * 8 + rr;
          const f32x4 v = *(const f32x4*)(resh + r * 132 + cc);
          float* orow = out + (size_t)(bm * 128 + p * 64 + r) * CDIM + gcol;
          *(f32x4*)orow = v;          // cached store (through L2)
          *(f32x4*)(orow + BC) = v;   // cached store (through L2)
        }
      }
    }
    __syncthreads();  // readers done before next pass overwrites resh
  }
#undef STAGE
}

extern "C" void kernel_launch(void* const* d_in, const int* in_sizes, int n_in,
                              void* d_out, int out_size, void* d_ws,
                              size_t ws_size, hipStream_t stream) {
  const float* feat = (const float*)d_in[0];
  // d_in[1] = label (int64) — unused by the reference math
  const float* w = (const float*)d_in[2];
  float* out = (float*)d_out;

  char* ws = (char*)d_ws;
  bf16_t* fb = (bf16_t*)ws;                        // 4096*512*2  = 4,194,304 B
  bf16_t* wb = (bf16_t*)(ws + 4194304);            // 10112*512*2 = 10,354,688 B
  float* f2 = (float*)(ws + 4194304 + 10354688);   // 16,384 B
  float* w2 = (float*)(ws + 4194304 + 10354688 + 16384);  // 40,448 B

  float* wout = out + (size_t)2 * BDIM * CDIM;  // weights passthrough segment

  prep<<<BDIM + CPAD, 256, 0, stream>>>(feat, w, fb, wb, f2, w2, wout);
  rbf_gemm<<<2528, 256, 0, stream>>>(fb, wb, f2, w2, out);
}

// Round 8
// 109.796 us; speedup vs baseline: 1.1784x; 1.1784x over previous
//
#include <hip/hip_runtime.h>
#include <hip/hip_bf16.h>
#include <stdint.h>

// Problem constants
#define BDIM 4096
#define CDIM 10000
#define DDIM 512
#define CPAD 10112  // 79 * 128, padded N so GEMM loads need no guards
#define NT 16       // K tiles (512 / 32)

typedef __bf16 bf16_t;
typedef __attribute__((ext_vector_type(2))) __bf16 bf16x2;
typedef __attribute__((ext_vector_type(8))) __bf16 bf16x8;
typedef __attribute__((ext_vector_type(2))) float f32x2;
typedef __attribute__((ext_vector_type(4))) float f32x4;

__device__ __forceinline__ void gl_lds16(const void* g, void* s) {
  // async global->LDS, 16B per lane; LDS dest = wave-uniform base + lane*16
  __builtin_amdgcn_global_load_lds(
      (const __attribute__((address_space(1))) void*)g,
      (__attribute__((address_space(3))) void*)s, 16, 0, 0);
}

// --- fused prep: rows [0,BDIM) = feat, rows [BDIM,BDIM+CPAD) = weights ---
__global__ __launch_bounds__(256) void prep(
    const float* __restrict__ feat, const float* __restrict__ w,
    bf16_t* __restrict__ fb, bf16_t* __restrict__ wb,
    float* __restrict__ f2, float* __restrict__ w2,
    float* __restrict__ wout) {
  const int b = blockIdx.x;
  const int t = threadIdx.x;
  __shared__ float red[4];
  if (b < BDIM) {
    const f32x2 v = ((const f32x2*)(feat + (size_t)b * DDIM))[t];
    bf16x2 o;
    o.x = (__bf16)v.x;
    o.y = (__bf16)v.y;
    ((bf16x2*)fb)[(size_t)b * (DDIM / 2) + t] = o;
    float ss = v.x * v.x + v.y * v.y;
#pragma unroll
    for (int off = 32; off > 0; off >>= 1) ss += __shfl_down(ss, off);
    if ((t & 63) == 0) red[t >> 6] = ss;
    __syncthreads();
    if (t == 0) f2[b] = red[0] + red[1] + red[2] + red[3];
  } else {
    const int row = b - BDIM;
    if (row < CDIM) {
      const f32x2 v = ((const f32x2*)(w + (size_t)row * DDIM))[t];
      __builtin_nontemporal_store(v, (f32x2*)(wout + (size_t)row * DDIM) + t);
      bf16x2 o;
      o.x = (__bf16)v.x;
      o.y = (__bf16)v.y;
      ((bf16x2*)wb)[(size_t)row * (DDIM / 2) + t] = o;
      float ss = v.x * v.x + v.y * v.y;
#pragma unroll
      for (int off = 32; off > 0; off >>= 1) ss += __shfl_down(ss, off);
      if ((t & 63) == 0) red[t >> 6] = ss;
      __syncthreads();
      if (t == 0) w2[row] = red[0] + red[1] + red[2] + red[3];
    } else {
      bf16x2 z;
      z.x = (__bf16)0.0f;
      z.y = (__bf16)0.0f;
      ((bf16x2*)wb)[(size_t)row * (DDIM / 2) + t] = z;
      if (t == 0) w2[row] = 0.0f;
    }
  }
}

// --- main GEMM + RBF epilogue ---
// 128x128 tile, BK=32, 4 waves (2x2), mfma(wfrag, ffrag) operand-swapped.
// R8: 2-buffer LDS (32 KB pool) minimum-2-phase schedule + resh shrunk to
// exactly 32 KB via XOR bank-swizzle -> 4 blocks/CU (__launch_bounds 256,4).
// Goal: cross-block phase overlap (store drain of one block under K-loop of
// three others). Epilogue: LDS-staged coalesced NT stores (R5/R7 winner).
__global__ __launch_bounds__(256, 4) void rbf_gemm(
    const bf16_t* __restrict__ A,   // [4096][512] bf16  (feat)
    const bf16_t* __restrict__ Bw,  // [10112][512] bf16 (weights, padded)
    const float* __restrict__ f2g, const float* __restrict__ w2g,
    float* __restrict__ out) {
  // pool: K-loop = 2 x [A(8KB) B(8KB)]; epilogue = resh 64x128 f32 (32KB)
  __shared__ __align__(16) char pool[32768];
  bf16_t* Pb = (bf16_t*)pool;  // elem layout: buf b: A @ b*8192, B @ b*8192+4096
  __shared__ float f2s[128];
  __shared__ float w2s[128];

  // 1-D grid, bijective XCD swizzle (nwg = 2528 = 8*316), bm fastest
  // (R5/R6 A/B: bm-fastest wins — concurrent blocks share the B-tile).
  const int bid = blockIdx.x;
  const int wg = (bid & 7) * (2528 / 8) + (bid >> 3);
  const int bm = wg & 31;  // 0..31 (M tiles) -- fastest within XCD chunk
  const int bn = wg >> 5;  // 0..78 (N tiles)
  const int t = threadIdx.x;
  const int lane = t & 63;

  if (t < 128)
    f2s[t] = f2g[bm * 128 + t];
  else
    w2s[t - 128] = w2g[bn * 128 + (t - 128)];

  // staging addressing: 4 threads x 16B per 32-elem row; 64 rows per call
  const int sr = t >> 2;
  const int sc = (t & 3) * 8;
  const bf16_t* ga0 = A + (size_t)(bm * 128 + sr) * DDIM + sc;
  const bf16_t* ga1 = ga0 + (size_t)64 * DDIM;
  const bf16_t* gb0 = Bw + (size_t)(bn * 128 + sr) * DDIM + sc;
  const bf16_t* gb1 = gb0 + (size_t)64 * DDIM;

  const int wv = t >> 6;
  const int wm = (wv >> 1) * 64;  // feat group of this wave
  const int wn = (wv & 1) * 64;   // weight group of this wave
  const int fr = lane & 15;
  const int k8 = (lane >> 4) * 8;

#define STAGE(b, kt)                                         \
  do {                                                       \
    const int k0_ = (kt) * 32;                               \
    bf16_t* Ab_ = Pb + (b) * 8192;                           \
    gl_lds16(ga0 + k0_, Ab_ + t * 8);                        \
    gl_lds16(ga1 + k0_, Ab_ + 2048 + t * 8);                 \
    gl_lds16(gb0 + k0_, Ab_ + 4096 + t * 8);                 \
    gl_lds16(gb1 + k0_, Ab_ + 4096 + 2048 + t * 8);          \
  } while (0)

  f32x4 acc[4][4];
#pragma unroll
  for (int i = 0; i < 4; ++i)
#pragma unroll
    for (int j = 0; j < 4; ++j) acc[i][j] = (f32x4){0.f, 0.f, 0.f, 0.f};

  STAGE(0, 0);
  __syncthreads();  // drains tile 0 + f2s/w2s

#pragma unroll
  for (int kt = 0; kt < NT; ++kt) {
    const int cur = kt & 1;
    if (kt + 1 < NT) STAGE(cur ^ 1, kt + 1);  // issue next-tile loads FIRST
    const bf16_t* Ab = Pb + cur * 8192;
    bf16x8 af[4], wf[4];
#pragma unroll
    for (int mi = 0; mi < 4; ++mi)
      af[mi] = *(const bf16x8*)(Ab + (wm + mi * 16 + fr) * 32 + k8);
#pragma unroll
    for (int ni = 0; ni < 4; ++ni)
      wf[ni] = *(const bf16x8*)(Ab + 4096 + (wn + ni * 16 + fr) * 32 + k8);
    __builtin_amdgcn_s_setprio(1);
#pragma unroll
    for (int mi = 0; mi < 4; ++mi)
#pragma unroll
      for (int ni = 0; ni < 4; ++ni)
        acc[mi][ni] = __builtin_amdgcn_mfma_f32_16x16x32_bf16(
            wf[ni], af[mi], acc[mi][ni], 0, 0, 0);  // swapped: D = W x F^T
    __builtin_amdgcn_s_setprio(0);
    if (kt + 1 < NT) __syncthreads();  // next buf landed; cur safe to reuse
  }

  __syncthreads();  // staging LDS now dead -> reuse as reshuffle tile

  // Coalesced epilogue. resh = 64 rows x 128 floats, XOR bank-swizzle:
  // float4-group g at row r lives at g^(r&31) (bijective per row -> same
  // conflict profile as padded stride, exactly 32 KB). Pass p covers output
  // rows [p*64, p*64+64), produced by the two waves with wm == p*64.
  float* resh = (float*)pool;
  const size_t BC = (size_t)BDIM * CDIM;
  const int m_l = lane & 15;
  const int c_l = (lane >> 4) * 4;

  for (int p = 0; p < 2; ++p) {
    if ((wv >> 1) == p) {
#pragma unroll
      for (int mi = 0; mi < 4; ++mi) {
        const int rl = mi * 16 + m_l;  // row within this 64-row half
        const float frow = f2s[wm + rl];
#pragma unroll
        for (int ni = 0; ni < 4; ++ni) {
          const int cl = wn + ni * 16 + c_l;
          f32x4 st;
#pragma unroll
          for (int j = 0; j < 4; ++j) {
            float m = frow + w2s[cl + j] - 2.0f * acc[mi][ni][j];
            m = fmaxf(m, 0.0f);
            st[j] = __expf(-0.01f * m);
          }
          *(f32x4*)(resh + rl * 128 + (((cl >> 2) ^ (rl & 31)) << 2)) = st;
        }
      }
    }
    __syncthreads();
    // stream 64 rows x 128 cols: 32 lanes x float4 = 512 B contiguous/row
    {
      const int rr = t >> 5;        // 0..7
      const int cc = (t & 31) * 4;  // 0..124
      const int gcol = bn * 128 + cc;
      if (gcol < CDIM) {
#pragma unroll
        for (int it = 0; it < 8; ++it) {
          const int r = it * 8 + rr;
          const f32x4 v =
              *(const f32x4*)(resh + r * 128 + (((cc >> 2) ^ (r & 31)) << 2));
          float* orow = out + (size_t)(bm * 128 + p * 64 + r) * CDIM + gcol;
          __builtin_nontemporal_store(v, (f32x4*)orow);
          __builtin_nontemporal_store(v, (f32x4*)(orow + BC));
        }
      }
    }
    __syncthreads();  // readers done before next pass overwrites resh
  }
#undef STAGE
}

extern "C" void kernel_launch(void* const* d_in, const int* in_sizes, int n_in,
                              void* d_out, int out_size, void* d_ws,
                              size_t ws_size, hipStream_t stream) {
  const float* feat = (const float*)d_in[0];
  // d_in[1] = label (int64) — unused by the reference math
  const float* w = (const float*)d_in[2];
  float* out = (float*)d_out;

  char* ws = (char*)d_ws;
  bf16_t* fb = (bf16_t*)ws;                        // 4096*512*2  = 4,194,304 B
  bf16_t* wb = (bf16_t*)(ws + 4194304);            // 10112*512*2 = 10,354,688 B
  float* f2 = (float*)(ws + 4194304 + 10354688);   // 16,384 B
  float* w2 = (float*)(ws + 4194304 + 10354688 + 16384);  // 40,448 B

  float* wout = out + (size_t)2 * BDIM * CDIM;  // weights passthrough segment

  prep<<<BDIM + CPAD, 256, 0, stream>>>(feat, w, fb, wb, f2, w2, wout);
  rbf_gemm<<<2528, 256, 0, stream>>>(fb, wb, f2, w2, out);
}